// Round 5
// baseline (2889.403 us; speedup 1.0000x reference)
//
#include <hip/hip_runtime.h>

#define SEQ 4096
#define BATCH 512
#define INP 8
#define HID 30
#define LOG2E 1.44269504088896340736f

typedef unsigned uint2v __attribute__((ext_vector_type(2)));

#define RCP(v)  __builtin_amdgcn_rcpf(v)
#if __has_builtin(__builtin_amdgcn_exp2f)
#define EXP2(v) __builtin_amdgcn_exp2f(v)
#else
#define EXP2(v) exp2f(v)
#endif

// permlane32_swap with both operands = v:
//   returns {lo_rep = [v_lo32 | v_lo32], hi_rep = [v_hi32 | v_hi32]}
__device__ __forceinline__ void rep_halves(float v, float& lo_rep, float& hi_rep) {
#if __has_builtin(__builtin_amdgcn_permlane32_swap)
    uint2v r = __builtin_amdgcn_permlane32_swap(
        __float_as_uint(v), __float_as_uint(v), false, false);
    lo_rep = __uint_as_float(r.x);
    hi_rep = __uint_as_float(r.y);
#else
    float other = __shfl_xor(v, 32, 64);
    bool hi = (threadIdx.x & 32) != 0;
    lo_rep = hi ? other : v;
    hi_rep = hi ? v : other;
#endif
}

template <int CTRL>
__device__ __forceinline__ float dpp_sum_step(float v) {
    return v + __uint_as_float(__builtin_amdgcn_update_dpp(
        0, (int)__float_as_uint(v), CTRL, 0xf, 0xf, true));
}

// Sum within each 32-lane group, pure VALU (no LDS / lgkmcnt stalls).
// Valid total in lanes 15,31 (and 47,63) of each group after the swap-add.
__device__ __forceinline__ float group32_reduce(float v) {
    v = dpp_sum_step<0x111>(v);  // row_shr:1
    v = dpp_sum_step<0x112>(v);  // row_shr:2
    v = dpp_sum_step<0x114>(v);  // row_shr:4
    v = dpp_sum_step<0x118>(v);  // row_shr:8 -> lane15=sum(0..15), lane31=sum(16..31)
#if __has_builtin(__builtin_amdgcn_permlane16_swap)
    uint2v r = __builtin_amdgcn_permlane16_swap(
        __float_as_uint(v), __float_as_uint(v), false, false);
    return __uint_as_float(r.x) + __uint_as_float(r.y);
#else
    return v + __shfl_xor(v, 16, 64);
#endif
}

// One wave = TWO batch chains (P = 2*blk, Q = 2*blk+1).
// lane = j (j<30): gate rows i_j (A) and g_j (B); lane 32+j: f_j (A), o_j (B).
// Weights/biases shared across chains; per-chain state: hs (30 SGPR), c, x regs.
// Two independent dep-graphs interleave in one in-order stream -> latency hiding.
// log2(e) folded into weights so activations use v_exp_f32 (exp2) directly.
__global__ __launch_bounds__(64)
__attribute__((amdgpu_waves_per_eu(1, 1)))
void lstm_chain_kernel(
    const float* __restrict__ x,     // [SEQ,BATCH,INP]
    const float* __restrict__ W_ih,  // [4H, INP]
    const float* __restrict__ W_hh,  // [4H, HID]
    const float* __restrict__ b_ih,  // [4H]
    const float* __restrict__ b_hh,  // [4H]
    const float* __restrict__ W_lin, // [1, HID]
    const float* __restrict__ b_lin, // [1]
    float* __restrict__ out)         // [SEQ,BATCH,1]
{
    const int lane = threadIdx.x;
    const int b0   = 2 * blockIdx.x;
    const int j    = lane & 31;
    const int half = lane >> 5;
    const int jc   = j < HID ? j : HID - 1;
    const int ra   = half * HID + jc;            // i (half0) / f (half1): sigmoid
    const int rb   = 2 * HID + half * HID + jc;  // g (half0, tanh) / o (half1, sigmoid)

    // exp2 folding scales: sigmoid(v)=rcp(1+2^(-log2e*v)); tanh(v)=1-2*rcp(1+2^(2*log2e*v))
    const float sA = -LOG2E;
    const float sB = half ? -LOG2E : 2.0f * LOG2E;
    const float sclB = half ? 1.0f : -2.0f;
    const float addB = half ? 0.0f : 1.0f;
    const float T2L  = 2.0f * LOG2E;  // for tanh(c)

    // ---- shared (per-lane) constant weights, pre-scaled, pinned in VGPRs ----
    float wih_a[INP], wih_b[INP];
#pragma unroll
    for (int i = 0; i < INP; ++i) {
        float wa = W_ih[ra * INP + i] * sA;
        float wb = W_ih[rb * INP + i] * sB;
        asm volatile("" : "+v"(wa));
        asm volatile("" : "+v"(wb));
        wih_a[i] = wa;
        wih_b[i] = wb;
    }
    float whh_a[HID], whh_b[HID];
#pragma unroll
    for (int k = 0; k < HID; ++k) {
        float wa = W_hh[ra * HID + k] * sA;
        float wb = W_hh[rb * HID + k] * sB;
        asm volatile("" : "+v"(wa));
        asm volatile("" : "+v"(wb));
        whh_a[k] = wa;
        whh_b[k] = wb;
    }
    const float bias_sa = (b_ih[ra] + b_hh[ra]) * sA;
    const float bias_sb = (b_ih[rb] + b_hh[rb]) * sB;
    const float blin    = b_lin[0];
    const float wlin    = (j < HID) ? W_lin[j] : 0.0f;

    // per-chain recurrent state
    float hsP[HID], hsQ[HID];
#pragma unroll
    for (int k = 0; k < HID; ++k) { hsP[k] = 0.0f; hsQ[k] = 0.0f; }
    float cP = 0.0f, cQ = 0.0f;

    // x for chains P,Q at time t is 64 contiguous bytes: 4 float4s
#define LOADX(PA, PB, QA, QB, TL) do {                                        \
    int _tl = (TL) < SEQ ? (TL) : SEQ - 1;                                    \
    const float4* _xp = (const float4*)(x + ((size_t)_tl * BATCH + b0) * INP);\
    PA = _xp[0]; PB = _xp[1]; QA = _xp[2]; QB = _xp[3];                       \
} while (0)

    float4 pA0, pB0, qA0, qB0, pA1, pB1, qA1, qB1;
    LOADX(pA0, pB0, qA0, qB0, 0);
    LOADX(pA1, pB1, qA1, qB1, 1);

#define STEP2(T, PA, PB, QA, QB) do {                                         \
    float uaP0 = bias_sa, ubP0 = bias_sb, uaQ0 = bias_sa, ubQ0 = bias_sb;     \
    float uaP1 = 0.f, ubP1 = 0.f, uaQ1 = 0.f, ubQ1 = 0.f;                     \
    uaP0 = fmaf((PA).x, wih_a[0], uaP0); ubP0 = fmaf((PA).x, wih_b[0], ubP0); \
    uaQ0 = fmaf((QA).x, wih_a[0], uaQ0); ubQ0 = fmaf((QA).x, wih_b[0], ubQ0); \
    uaP0 = fmaf((PA).y, wih_a[1], uaP0); ubP0 = fmaf((PA).y, wih_b[1], ubP0); \
    uaQ0 = fmaf((QA).y, wih_a[1], uaQ0); ubQ0 = fmaf((QA).y, wih_b[1], ubQ0); \
    uaP0 = fmaf((PA).z, wih_a[2], uaP0); ubP0 = fmaf((PA).z, wih_b[2], ubP0); \
    uaQ0 = fmaf((QA).z, wih_a[2], uaQ0); ubQ0 = fmaf((QA).z, wih_b[2], ubQ0); \
    uaP0 = fmaf((PA).w, wih_a[3], uaP0); ubP0 = fmaf((PA).w, wih_b[3], ubP0); \
    uaQ0 = fmaf((QA).w, wih_a[3], uaQ0); ubQ0 = fmaf((QA).w, wih_b[3], ubQ0); \
    uaP1 = fmaf((PB).x, wih_a[4], uaP1); ubP1 = fmaf((PB).x, wih_b[4], ubP1); \
    uaQ1 = fmaf((QB).x, wih_a[4], uaQ1); ubQ1 = fmaf((QB).x, wih_b[4], ubQ1); \
    uaP1 = fmaf((PB).y, wih_a[5], uaP1); ubP1 = fmaf((PB).y, wih_b[5], ubP1); \
    uaQ1 = fmaf((QB).y, wih_a[5], uaQ1); ubQ1 = fmaf((QB).y, wih_b[5], ubQ1); \
    uaP1 = fmaf((PB).z, wih_a[6], uaP1); ubP1 = fmaf((PB).z, wih_b[6], ubP1); \
    uaQ1 = fmaf((QB).z, wih_a[6], uaQ1); ubQ1 = fmaf((QB).z, wih_b[6], ubQ1); \
    uaP1 = fmaf((PB).w, wih_a[7], uaP1); ubP1 = fmaf((PB).w, wih_b[7], ubP1); \
    uaQ1 = fmaf((QB).w, wih_a[7], uaQ1); ubQ1 = fmaf((QB).w, wih_b[7], ubQ1); \
    _Pragma("unroll")                                                         \
    for (int k = 0; k < HID; k += 2) {                                        \
        uaP0 = fmaf(hsP[k],   whh_a[k],   uaP0);                              \
        ubP0 = fmaf(hsP[k],   whh_b[k],   ubP0);                              \
        uaQ0 = fmaf(hsQ[k],   whh_a[k],   uaQ0);                              \
        ubQ0 = fmaf(hsQ[k],   whh_b[k],   ubQ0);                              \
        uaP1 = fmaf(hsP[k+1], whh_a[k+1], uaP1);                              \
        ubP1 = fmaf(hsP[k+1], whh_b[k+1], ubP1);                              \
        uaQ1 = fmaf(hsQ[k+1], whh_a[k+1], uaQ1);                              \
        ubQ1 = fmaf(hsQ[k+1], whh_b[k+1], ubQ1);                              \
    }                                                                         \
    float uaP = uaP0 + uaP1, ubP = ubP0 + ubP1;                               \
    float uaQ = uaQ0 + uaQ1, ubQ = ubQ0 + ubQ1;                               \
    float AvP = RCP(1.0f + EXP2(uaP));                                        \
    float AvQ = RCP(1.0f + EXP2(uaQ));                                        \
    float sBP = RCP(1.0f + EXP2(ubP));                                        \
    float sBQ = RCP(1.0f + EXP2(ubQ));                                        \
    float BvP = fmaf(sBP, sclB, addB);                                        \
    float BvQ = fmaf(sBQ, sclB, addB);                                        \
    float iiP, ffP, ggP, ooP, iiQ, ffQ, ggQ, ooQ;                             \
    rep_halves(AvP, iiP, ffP); rep_halves(BvP, ggP, ooP);                     \
    rep_halves(AvQ, iiQ, ffQ); rep_halves(BvQ, ggQ, ooQ);                     \
    cP = fmaf(ffP, cP, iiP * ggP);                                            \
    cQ = fmaf(ffQ, cQ, iiQ * ggQ);                                            \
    float scP = RCP(1.0f + EXP2(cP * T2L));                                   \
    float scQ = RCP(1.0f + EXP2(cQ * T2L));                                   \
    float hP = ooP * fmaf(scP, -2.0f, 1.0f);                                  \
    float hQ = ooQ * fmaf(scQ, -2.0f, 1.0f);                                  \
    float rP = group32_reduce(hP * wlin);                                     \
    float rQ = group32_reduce(hQ * wlin);                                     \
    if (lane == 31) {                                                         \
        float2 o2; o2.x = rP + blin; o2.y = rQ + blin;                        \
        *(float2*)(out + (size_t)(T) * BATCH + b0) = o2;                      \
    }                                                                         \
    _Pragma("unroll")                                                         \
    for (int k = 0; k < HID; ++k) {                                           \
        hsP[k] = __uint_as_float((unsigned)__builtin_amdgcn_readlane(         \
                     (int)__float_as_uint(hP), k));                           \
        hsQ[k] = __uint_as_float((unsigned)__builtin_amdgcn_readlane(         \
                     (int)__float_as_uint(hQ), k));                           \
    }                                                                         \
} while (0)

    for (int t = 0; t < SEQ; t += 2) {
        STEP2(t, pA0, pB0, qA0, qB0);
        LOADX(pA0, pB0, qA0, qB0, t + 2);
        STEP2(t + 1, pA1, pB1, qA1, qB1);
        LOADX(pA1, pB1, qA1, qB1, t + 3);
    }
#undef STEP2
#undef LOADX
}

extern "C" void kernel_launch(void* const* d_in, const int* in_sizes, int n_in,
                              void* d_out, int out_size, void* d_ws, size_t ws_size,
                              hipStream_t stream) {
    const float* x     = (const float*)d_in[0];
    const float* W_ih  = (const float*)d_in[1];
    const float* W_hh  = (const float*)d_in[2];
    const float* b_ih  = (const float*)d_in[3];
    const float* b_hh  = (const float*)d_in[4];
    const float* W_lin = (const float*)d_in[5];
    const float* b_lin = (const float*)d_in[6];
    float* out = (float*)d_out;

    lstm_chain_kernel<<<dim3(BATCH / 2), dim3(64), 0, stream>>>(
        x, W_ih, W_hh, b_ih, b_hh, W_lin, b_lin, out);
}

// Round 6
// 1513.928 us; speedup vs baseline: 1.9085x; 1.9085x over previous
//
#include <hip/hip_runtime.h>

#define SEQ 4096
#define BATCH 512
#define INP 8
#define HID 30
#define LOG2E 1.44269504088896340736f

typedef unsigned uint2v __attribute__((ext_vector_type(2)));

#define RCP(v)  __builtin_amdgcn_rcpf(v)
#if __has_builtin(__builtin_amdgcn_exp2f)
#define EXP2(v) __builtin_amdgcn_exp2f(v)
#else
#define EXP2(v) exp2f(v)
#endif

// permlane32_swap with both operands = v:
//   returns {lo_rep = [v_lo32 | v_lo32], hi_rep = [v_hi32 | v_hi32]}
__device__ __forceinline__ void rep_halves(float v, float& lo_rep, float& hi_rep) {
#if __has_builtin(__builtin_amdgcn_permlane32_swap)
    uint2v r = __builtin_amdgcn_permlane32_swap(
        __float_as_uint(v), __float_as_uint(v), false, false);
    lo_rep = __uint_as_float(r.x);
    hi_rep = __uint_as_float(r.y);
#else
    float other = __shfl_xor(v, 32, 64);
    bool hi = (threadIdx.x & 32) != 0;
    lo_rep = hi ? other : v;
    hi_rep = hi ? v : other;
#endif
}

template <int CTRL>
__device__ __forceinline__ float dpp_sum_step(float v) {
    return v + __uint_as_float(__builtin_amdgcn_update_dpp(
        0, (int)__float_as_uint(v), CTRL, 0xf, 0xf, true));
}

// Sum within each 32-lane group, pure VALU (no LDS / lgkmcnt stalls).
// Total valid in (at least) lanes 16..31 of each 32-group after swap-add.
__device__ __forceinline__ float group32_reduce(float v) {
    v = dpp_sum_step<0x111>(v);  // row_shr:1
    v = dpp_sum_step<0x112>(v);  // row_shr:2
    v = dpp_sum_step<0x114>(v);  // row_shr:4
    v = dpp_sum_step<0x118>(v);  // row_shr:8 -> lane15=sum(0..15), lane31=sum(16..31)
#if __has_builtin(__builtin_amdgcn_permlane16_swap)
    uint2v r = __builtin_amdgcn_permlane16_swap(
        __float_as_uint(v), __float_as_uint(v), false, false);
    return __uint_as_float(r.x) + __uint_as_float(r.y);
#else
    return v + __shfl_xor(v, 16, 64);
#endif
}

// One wave per batch chain (512 waves). No per-step global stores: y is
// buffered in LDS and dumped after the recurrence, so the K-loop's vmcnt
// queue holds only x prefetch loads (stores would otherwise serialize the
// in-order vmcnt waits every step).
// lane = j (j<30): gate rows i_j (A), g_j (B); lane 32+j: f_j (A), o_j (B).
// h broadcast via 30x v_readlane -> SGPRs; gate FMA = v_fma(sgpr,vgpr,vgpr).
// log2(e) folded into weights: activations use v_exp_f32 (=exp2) directly.
__global__ __launch_bounds__(64)
__attribute__((amdgpu_waves_per_eu(1, 1)))
void lstm_chain_kernel(
    const float* __restrict__ x,     // [SEQ,BATCH,INP]
    const float* __restrict__ W_ih,  // [4H, INP]
    const float* __restrict__ W_hh,  // [4H, HID]
    const float* __restrict__ b_ih,  // [4H]
    const float* __restrict__ b_hh,  // [4H]
    const float* __restrict__ W_lin, // [1, HID]
    const float* __restrict__ b_lin, // [1]
    float* __restrict__ out)         // [SEQ,BATCH,1]
{
    const int lane = threadIdx.x;
    // XCD-aware swizzle: consecutive chains (sharing 64B x-lines and 32B
    // out-sectors) land on the same XCD's L2.
    const int g    = blockIdx.x;
    const int b    = (g & 7) * (BATCH / 8) + (g >> 3);
    const int j    = lane & 31;
    const int half = lane >> 5;
    const int jc   = j < HID ? j : HID - 1;
    const int ra   = half * HID + jc;            // i (half0) / f (half1): sigmoid
    const int rb   = 2 * HID + half * HID + jc;  // g (half0, tanh) / o (half1, sigmoid)

    // exp2 folding: sigmoid(v)=rcp(1+2^(-log2e*v)); tanh(v)=1-2*rcp(1+2^(2*log2e*v))
    const float sA   = -LOG2E;
    const float sB   = half ? -LOG2E : 2.0f * LOG2E;
    const float sclB = half ? 1.0f : -2.0f;
    const float addB = half ? 0.0f : 1.0f;
    const float T2L  = 2.0f * LOG2E;  // for tanh(c)

    // ---- per-lane constant weights, pre-scaled, pinned in VGPRs ----
    float wih_a[INP], wih_b[INP];
#pragma unroll
    for (int i = 0; i < INP; ++i) {
        float wa = W_ih[ra * INP + i] * sA;
        float wb = W_ih[rb * INP + i] * sB;
        asm volatile("" : "+v"(wa));
        asm volatile("" : "+v"(wb));
        wih_a[i] = wa;
        wih_b[i] = wb;
    }
    float whh_a[HID], whh_b[HID];
#pragma unroll
    for (int k = 0; k < HID; ++k) {
        float wa = W_hh[ra * HID + k] * sA;
        float wb = W_hh[rb * HID + k] * sB;
        asm volatile("" : "+v"(wa));
        asm volatile("" : "+v"(wb));
        whh_a[k] = wa;
        whh_b[k] = wb;
    }
    const float bias_sa = (b_ih[ra] + b_hh[ra]) * sA;
    const float bias_sb = (b_ih[rb] + b_hh[rb]) * sB;
    const float blin    = b_lin[0];
    const float wlin    = (j < HID) ? W_lin[j] : 0.0f;

    // y ring: one float per timestep, dumped after the loop
    __shared__ float s_y[SEQ];

    // recurrent state: h broadcast in SGPRs, c per-lane (uniform content)
    float hs[HID];
#pragma unroll
    for (int k = 0; k < HID; ++k) hs[k] = 0.0f;
    float c = 0.0f;

#define LOADX(XA, XB, TL) do {                                                \
    int _tl = (TL) < SEQ ? (TL) : SEQ - 1;                                    \
    const float4* _xp = (const float4*)(x + ((size_t)_tl * BATCH + b) * INP); \
    XA = _xp[0]; XB = _xp[1];                                                 \
} while (0)

    float4 xA0, xB0, xA1, xB1, xA2, xB2, xA3, xB3;
    LOADX(xA0, xB0, 0);
    LOADX(xA1, xB1, 1);
    LOADX(xA2, xB2, 2);
    LOADX(xA3, xB3, 3);

#define STEP(T, XA, XB) do {                                                  \
    float ua0 = bias_sa, ub0 = bias_sb;                                       \
    float ua1 = 0.0f,    ub1 = 0.0f;                                          \
    ua0 = fmaf((XA).x, wih_a[0], ua0);  ub0 = fmaf((XA).x, wih_b[0], ub0);    \
    ua0 = fmaf((XA).y, wih_a[1], ua0);  ub0 = fmaf((XA).y, wih_b[1], ub0);    \
    ua0 = fmaf((XA).z, wih_a[2], ua0);  ub0 = fmaf((XA).z, wih_b[2], ub0);    \
    ua0 = fmaf((XA).w, wih_a[3], ua0);  ub0 = fmaf((XA).w, wih_b[3], ub0);    \
    ua1 = fmaf((XB).x, wih_a[4], ua1);  ub1 = fmaf((XB).x, wih_b[4], ub1);    \
    ua1 = fmaf((XB).y, wih_a[5], ua1);  ub1 = fmaf((XB).y, wih_b[5], ub1);    \
    ua1 = fmaf((XB).z, wih_a[6], ua1);  ub1 = fmaf((XB).z, wih_b[6], ub1);    \
    ua1 = fmaf((XB).w, wih_a[7], ua1);  ub1 = fmaf((XB).w, wih_b[7], ub1);    \
    _Pragma("unroll")                                                         \
    for (int k = 0; k < HID; k += 2) {                                        \
        ua0 = fmaf(hs[k],   whh_a[k],   ua0);                                 \
        ub0 = fmaf(hs[k],   whh_b[k],   ub0);                                 \
        ua1 = fmaf(hs[k+1], whh_a[k+1], ua1);                                 \
        ub1 = fmaf(hs[k+1], whh_b[k+1], ub1);                                 \
    }                                                                         \
    float ua = ua0 + ua1, ub = ub0 + ub1;                                     \
    float Av = RCP(1.0f + EXP2(ua));                                          \
    float sBv = RCP(1.0f + EXP2(ub));                                         \
    float Bv = fmaf(sBv, sclB, addB);                                         \
    float ii, ff, gg, oo;                                                     \
    rep_halves(Av, ii, ff);                                                   \
    rep_halves(Bv, gg, oo);                                                   \
    c = fmaf(ff, c, ii * gg);                                                 \
    float sc = RCP(1.0f + EXP2(c * T2L));                                     \
    float h  = oo * fmaf(sc, -2.0f, 1.0f);                                    \
    float r  = group32_reduce(h * wlin);                                      \
    if (lane == 31) s_y[T] = r + blin;                                        \
    _Pragma("unroll")                                                         \
    for (int k = 0; k < HID; ++k)                                             \
        hs[k] = __uint_as_float((unsigned)__builtin_amdgcn_readlane(          \
                    (int)__float_as_uint(h), k));                             \
} while (0)

    for (int t = 0; t < SEQ; t += 4) {
        STEP(t + 0, xA0, xB0);  LOADX(xA0, xB0, t + 4);
        STEP(t + 1, xA1, xB1);  LOADX(xA1, xB1, t + 5);
        STEP(t + 2, xA2, xB2);  LOADX(xA2, xB2, t + 6);
        STEP(t + 3, xA3, xB3);  LOADX(xA3, xB3, t + 7);
    }
#undef STEP
#undef LOADX

    // ---- dump y: 4096 floats, 16 iterations of (ds_read_b128 + 4 stores) ----
    __syncthreads();  // single wave; orders the last ds_write before reads
    const float4* s_y4 = reinterpret_cast<const float4*>(s_y);
#pragma unroll 4
    for (int it = 0; it < SEQ / 256; ++it) {
        int tbase = it * 256 + lane * 4;
        float4 v = s_y4[tbase >> 2];
        out[(size_t)(tbase + 0) * BATCH + b] = v.x;
        out[(size_t)(tbase + 1) * BATCH + b] = v.y;
        out[(size_t)(tbase + 2) * BATCH + b] = v.z;
        out[(size_t)(tbase + 3) * BATCH + b] = v.w;
    }
}

extern "C" void kernel_launch(void* const* d_in, const int* in_sizes, int n_in,
                              void* d_out, int out_size, void* d_ws, size_t ws_size,
                              hipStream_t stream) {
    const float* x     = (const float*)d_in[0];
    const float* W_ih  = (const float*)d_in[1];
    const float* W_hh  = (const float*)d_in[2];
    const float* b_ih  = (const float*)d_in[3];
    const float* b_hh  = (const float*)d_in[4];
    const float* W_lin = (const float*)d_in[5];
    const float* b_lin = (const float*)d_in[6];
    float* out = (float*)d_out;

    lstm_chain_kernel<<<dim3(BATCH), dim3(64), 0, stream>>>(
        x, W_ih, W_hh, b_ih, b_hh, W_lin, b_lin, out);
}

// Round 7
// 1393.872 us; speedup vs baseline: 2.0729x; 1.0861x over previous
//
#include <hip/hip_runtime.h>

#define SEQ 4096
#define BATCH 512
#define INP 8
#define HID 30
#define LOG2E 1.44269504088896340736f

typedef float f32x2 __attribute__((ext_vector_type(2)));
typedef float f32x4 __attribute__((ext_vector_type(4)));
typedef unsigned uint2v __attribute__((ext_vector_type(2)));

#define RCP(v)  __builtin_amdgcn_rcpf(v)
#if __has_builtin(__builtin_amdgcn_exp2f)
#define EXP2(v) __builtin_amdgcn_exp2f(v)
#else
#define EXP2(v) exp2f(v)
#endif
#define PKFMA(a, b, c) __builtin_elementwise_fma(a, b, c)

// permlane32_swap with both operands = v:
//   returns {lo_rep = [v_lo32 | v_lo32], hi_rep = [v_hi32 | v_hi32]}
__device__ __forceinline__ void rep_halves(float v, float& lo_rep, float& hi_rep) {
#if __has_builtin(__builtin_amdgcn_permlane32_swap)
    uint2v r = __builtin_amdgcn_permlane32_swap(
        __float_as_uint(v), __float_as_uint(v), false, false);
    lo_rep = __uint_as_float(r.x);
    hi_rep = __uint_as_float(r.y);
#else
    float other = __shfl_xor(v, 32, 64);
    bool hi = (threadIdx.x & 32) != 0;
    lo_rep = hi ? other : v;
    hi_rep = hi ? v : other;
#endif
}

template <int CTRL>
__device__ __forceinline__ float dpp_sum_step(float v) {
    return v + __uint_as_float(__builtin_amdgcn_update_dpp(
        0, (int)__float_as_uint(v), CTRL, 0xf, 0xf, true));
}

// Sum within each 32-lane group, pure VALU (no LDS / lgkmcnt stalls).
__device__ __forceinline__ float group32_reduce(float v) {
    v = dpp_sum_step<0x111>(v);  // row_shr:1
    v = dpp_sum_step<0x112>(v);  // row_shr:2
    v = dpp_sum_step<0x114>(v);  // row_shr:4
    v = dpp_sum_step<0x118>(v);  // row_shr:8 -> lane15=sum(0..15), lane31=sum(16..31)
#if __has_builtin(__builtin_amdgcn_permlane16_swap)
    uint2v r = __builtin_amdgcn_permlane16_swap(
        __float_as_uint(v), __float_as_uint(v), false, false);
    return __uint_as_float(r.x) + __uint_as_float(r.y);
#else
    return v + __shfl_xor(v, 16, 64);
#endif
}

// One wave per batch chain (512 waves). y buffered in LDS, dumped at the end
// (keeps the K-loop's vmcnt queue loads-only). h broadcast via LDS round trip
// (stride-1 ds_write by all lanes, 8x uniform-address ds_read_b128 back into
// f32x2 pairs) feeding v_pk_fma_f32 packed matvec (38 packed vs 76 scalar).
// LDS ops within one wave execute in order -> no barrier needed.
__global__ __launch_bounds__(64)
__attribute__((amdgpu_waves_per_eu(1, 1)))
void lstm_chain_kernel(
    const float* __restrict__ x,     // [SEQ,BATCH,INP]
    const float* __restrict__ W_ih,  // [4H, INP]
    const float* __restrict__ W_hh,  // [4H, HID]
    const float* __restrict__ b_ih,  // [4H]
    const float* __restrict__ b_hh,  // [4H]
    const float* __restrict__ W_lin, // [1, HID]
    const float* __restrict__ b_lin, // [1]
    float* __restrict__ out)         // [SEQ,BATCH,1]
{
    const int lane = threadIdx.x;
    // XCD-aware swizzle: consecutive chains (sharing 64B x-lines and 32B
    // out-sectors) land on the same XCD's L2.
    const int g    = blockIdx.x;
    const int b    = (g & 7) * (BATCH / 8) + (g >> 3);
    const int j    = lane & 31;
    const int half = lane >> 5;
    const int jc   = j < HID ? j : HID - 1;
    const int ra   = half * HID + jc;            // i (half0) / f (half1): sigmoid
    const int rb   = 2 * HID + half * HID + jc;  // g (half0, tanh) / o (half1, sigmoid)

    // exp2 folding: sigmoid(v)=rcp(1+2^(-log2e*v)); tanh(v)=1-2*rcp(1+2^(2*log2e*v))
    const float sA   = -LOG2E;
    const float sB   = half ? -LOG2E : 2.0f * LOG2E;
    const float sclB = half ? 1.0f : -2.0f;
    const float addB = half ? 0.0f : 1.0f;
    const float T2L  = 2.0f * LOG2E;  // for tanh(c)

    // ---- packed per-lane weights, pre-scaled, pinned in VGPR pairs ----
    f32x2 wih2_a[INP / 2], wih2_b[INP / 2];
#pragma unroll
    for (int i = 0; i < INP / 2; ++i) {
        f32x2 wa = { W_ih[ra * INP + 2 * i] * sA, W_ih[ra * INP + 2 * i + 1] * sA };
        f32x2 wb = { W_ih[rb * INP + 2 * i] * sB, W_ih[rb * INP + 2 * i + 1] * sB };
        asm volatile("" : "+v"(wa));
        asm volatile("" : "+v"(wb));
        wih2_a[i] = wa;
        wih2_b[i] = wb;
    }
    f32x2 whh2_a[HID / 2], whh2_b[HID / 2];
#pragma unroll
    for (int k = 0; k < HID / 2; ++k) {
        f32x2 wa = { W_hh[ra * HID + 2 * k] * sA, W_hh[ra * HID + 2 * k + 1] * sA };
        f32x2 wb = { W_hh[rb * HID + 2 * k] * sB, W_hh[rb * HID + 2 * k + 1] * sB };
        asm volatile("" : "+v"(wa));
        asm volatile("" : "+v"(wb));
        whh2_a[k] = wa;
        whh2_b[k] = wb;
    }
    const float bias_sa = (b_ih[ra] + b_hh[ra]) * sA;
    const float bias_sb = (b_ih[rb] + b_hh[rb]) * sB;
    const float blin    = b_lin[0];
    const float wlin    = (j < HID) ? W_lin[j] : 0.0f;

    __shared__ float s_y[SEQ];
    __shared__ __align__(16) float s_h[64];  // 0..29 valid; 30..63 pad/dump

    // h broadcast pairs (registers), c per-lane
    f32x2 hrf2[HID / 2];
#pragma unroll
    for (int k = 0; k < HID / 2; ++k) hrf2[k] = (f32x2){0.0f, 0.0f};
    float c = 0.0f;

#define LOADX(XA, XB, TL) do {                                                \
    int _tl = (TL) < SEQ ? (TL) : SEQ - 1;                                    \
    const f32x4* _xp = (const f32x4*)(x + ((size_t)_tl * BATCH + b) * INP);   \
    XA = _xp[0]; XB = _xp[1];                                                 \
} while (0)

    f32x4 xA0, xB0, xA1, xB1, xA2, xB2, xA3, xB3;
    LOADX(xA0, xB0, 0);
    LOADX(xA1, xB1, 1);
    LOADX(xA2, xB2, 2);
    LOADX(xA3, xB3, 3);

    const f32x4* s_h4 = reinterpret_cast<const f32x4*>(s_h);

#define STEP(T, XA, XB) do {                                                  \
    f32x2 A0 = {bias_sa, 0.0f}, B0 = {bias_sb, 0.0f};                         \
    f32x2 A1 = {0.0f, 0.0f},    B1 = {0.0f, 0.0f};                            \
    f32x2 x01 = __builtin_shufflevector(XA, XA, 0, 1);                        \
    f32x2 x23 = __builtin_shufflevector(XA, XA, 2, 3);                        \
    f32x2 x45 = __builtin_shufflevector(XB, XB, 0, 1);                        \
    f32x2 x67 = __builtin_shufflevector(XB, XB, 2, 3);                        \
    A0 = PKFMA(x01, wih2_a[0], A0);  B0 = PKFMA(x01, wih2_b[0], B0);          \
    A1 = PKFMA(x23, wih2_a[1], A1);  B1 = PKFMA(x23, wih2_b[1], B1);          \
    A0 = PKFMA(x45, wih2_a[2], A0);  B0 = PKFMA(x45, wih2_b[2], B0);          \
    A1 = PKFMA(x67, wih2_a[3], A1);  B1 = PKFMA(x67, wih2_b[3], B1);          \
    _Pragma("unroll")                                                         \
    for (int k = 0; k < HID / 2 - 1; k += 2) {                                \
        A0 = PKFMA(hrf2[k],   whh2_a[k],   A0);                               \
        B0 = PKFMA(hrf2[k],   whh2_b[k],   B0);                               \
        A1 = PKFMA(hrf2[k+1], whh2_a[k+1], A1);                               \
        B1 = PKFMA(hrf2[k+1], whh2_b[k+1], B1);                               \
    }                                                                         \
    A0 = PKFMA(hrf2[HID/2-1], whh2_a[HID/2-1], A0);                           \
    B0 = PKFMA(hrf2[HID/2-1], whh2_b[HID/2-1], B0);                           \
    f32x2 As = A0 + A1;  float ua = As.x + As.y;                              \
    f32x2 Bs = B0 + B1;  float ub = Bs.x + Bs.y;                              \
    float Av  = RCP(1.0f + EXP2(ua));                                         \
    float sBv = RCP(1.0f + EXP2(ub));                                         \
    float Bv  = fmaf(sBv, sclB, addB);                                        \
    float ii, ff, gg, oo;                                                     \
    rep_halves(Av, ii, ff);                                                   \
    rep_halves(Bv, gg, oo);                                                   \
    c = fmaf(ff, c, ii * gg);                                                 \
    float sc = RCP(1.0f + EXP2(c * T2L));                                     \
    float h  = oo * fmaf(sc, -2.0f, 1.0f);                                    \
    s_h[lane] = h;  /* lanes 0..29 valid; 30..63 land in pad (same values) */ \
    asm volatile("" ::: "memory");  /* keep ds_write before ds_reads */       \
    float p = group32_reduce(h * wlin);                                       \
    if (lane == 31) s_y[T] = p + blin;                                        \
    f32x4 hv0 = s_h4[0], hv1 = s_h4[1], hv2 = s_h4[2], hv3 = s_h4[3];         \
    f32x4 hv4 = s_h4[4], hv5 = s_h4[5], hv6 = s_h4[6], hv7 = s_h4[7];         \
    hrf2[0]  = __builtin_shufflevector(hv0, hv0, 0, 1);                       \
    hrf2[1]  = __builtin_shufflevector(hv0, hv0, 2, 3);                       \
    hrf2[2]  = __builtin_shufflevector(hv1, hv1, 0, 1);                       \
    hrf2[3]  = __builtin_shufflevector(hv1, hv1, 2, 3);                       \
    hrf2[4]  = __builtin_shufflevector(hv2, hv2, 0, 1);                       \
    hrf2[5]  = __builtin_shufflevector(hv2, hv2, 2, 3);                       \
    hrf2[6]  = __builtin_shufflevector(hv3, hv3, 0, 1);                       \
    hrf2[7]  = __builtin_shufflevector(hv3, hv3, 2, 3);                       \
    hrf2[8]  = __builtin_shufflevector(hv4, hv4, 0, 1);                       \
    hrf2[9]  = __builtin_shufflevector(hv4, hv4, 2, 3);                       \
    hrf2[10] = __builtin_shufflevector(hv5, hv5, 0, 1);                       \
    hrf2[11] = __builtin_shufflevector(hv5, hv5, 2, 3);                       \
    hrf2[12] = __builtin_shufflevector(hv6, hv6, 0, 1);                       \
    hrf2[13] = __builtin_shufflevector(hv6, hv6, 2, 3);                       \
    hrf2[14] = __builtin_shufflevector(hv7, hv7, 0, 1);                       \
} while (0)

    for (int t = 0; t < SEQ; t += 4) {
        STEP(t + 0, xA0, xB0);  LOADX(xA0, xB0, t + 4);
        STEP(t + 1, xA1, xB1);  LOADX(xA1, xB1, t + 5);
        STEP(t + 2, xA2, xB2);  LOADX(xA2, xB2, t + 6);
        STEP(t + 3, xA3, xB3);  LOADX(xA3, xB3, t + 7);
    }
#undef STEP
#undef LOADX

    // ---- dump y: 4096 floats, 16 iterations of (ds_read_b128 + 4 stores) ----
    __syncthreads();  // single wave; orders the last ds_write before reads
    const float4* s_y4 = reinterpret_cast<const float4*>(s_y);
#pragma unroll 4
    for (int it = 0; it < SEQ / 256; ++it) {
        int tbase = it * 256 + lane * 4;
        float4 v = s_y4[tbase >> 2];
        out[(size_t)(tbase + 0) * BATCH + b] = v.x;
        out[(size_t)(tbase + 1) * BATCH + b] = v.y;
        out[(size_t)(tbase + 2) * BATCH + b] = v.z;
        out[(size_t)(tbase + 3) * BATCH + b] = v.w;
    }
}

extern "C" void kernel_launch(void* const* d_in, const int* in_sizes, int n_in,
                              void* d_out, int out_size, void* d_ws, size_t ws_size,
                              hipStream_t stream) {
    const float* x     = (const float*)d_in[0];
    const float* W_ih  = (const float*)d_in[1];
    const float* W_hh  = (const float*)d_in[2];
    const float* b_ih  = (const float*)d_in[3];
    const float* b_hh  = (const float*)d_in[4];
    const float* W_lin = (const float*)d_in[5];
    const float* b_lin = (const float*)d_in[6];
    float* out = (float*)d_out;

    lstm_chain_kernel<<<dim3(BATCH), dim3(64), 0, stream>>>(
        x, W_ih, W_hh, b_ih, b_hh, W_lin, b_lin, out);
}